// Round 4
// baseline (299.276 us; speedup 1.0000x reference)
//
#include <hip/hip_runtime.h>
#include <math.h>

#define BB   128
#define CC   5
#define PP   5
#define LL   5
#define DD   128
#define NSEQ 640
#define GATES 512
#define IN0  384
#define HPAD 136

typedef __attribute__((ext_vector_type(8))) short short8;   // 8 bf16
typedef __attribute__((ext_vector_type(4))) float f32x4;    // MFMA C/D

__device__ __forceinline__ float sigf(float x){ return 1.0f/(1.0f+__expf(-x)); }
__device__ __forceinline__ float tanhfast(float x){ return 1.0f - 2.0f/(__expf(2.0f*x)+1.0f); }

__device__ __forceinline__ unsigned short f2bf(float x){
    union { float f; unsigned u; } v; v.f = x;
    unsigned r = v.u + 0x7FFF + ((v.u >> 16) & 1);   // RNE
    return (unsigned short)(r >> 16);
}

// ---- prep: weights -> bf16 MFMA B-fragment layout; biases; zero psum --------
// F[((p*KT + kt)*32 + gt)*512 + lane*8 + j] = bf16( W[p][gt*16+(lane&15)][kt*32+(lane>>4)*8+j] )
__global__ void prep_kernel(const float* __restrict__ Wih0, const float* __restrict__ Whh0,
                            const float* __restrict__ Wih1, const float* __restrict__ Whh1,
                            const float* __restrict__ bih0, const float* __restrict__ bhh0,
                            const float* __restrict__ bih1, const float* __restrict__ bhh1,
                            unsigned short* __restrict__ F0, unsigned short* __restrict__ F1,
                            unsigned short* __restrict__ F2, unsigned short* __restrict__ F3,
                            float* __restrict__ b0, float* __restrict__ b1c,
                            float* __restrict__ psum){
    int id = blockIdx.x*256 + threadIdx.x;
    const int NF0 = PP*12*32*64;     // 122880
    const int NFH = PP*4*32*64;      // 40960
    if (id < NF0 + 3*NFH){
        const float* src; unsigned short* dst; int K, KT, fid;
        if (id < NF0){ src = Wih0; dst = F0; K = IN0; KT = 12; fid = id; }
        else {
            int j = id - NF0; int m = j / NFH; fid = j % NFH; K = DD; KT = 4;
            src = (m==0)?Whh0:(m==1)?Wih1:Whh1;
            dst = (m==0)?F1:(m==1)?F2:F3;
        }
        int lane = fid & 63; int rem = fid >> 6;
        int gt = rem & 31; rem >>= 5;
        int kt = rem % KT; int p = rem / KT;
        int g  = gt*16 + (lane & 15);
        int k0 = kt*32 + (lane >> 4)*8;
        const float* s = src + (size_t)(p*GATES + g)*K + k0;
        float4 x0 = *(const float4*)s;
        float4 x1 = *(const float4*)(s+4);
        uint4 o;
        o.x = f2bf(x0.x) | ((unsigned)f2bf(x0.y)<<16);
        o.y = f2bf(x0.z) | ((unsigned)f2bf(x0.w)<<16);
        o.z = f2bf(x1.x) | ((unsigned)f2bf(x1.y)<<16);
        o.w = f2bf(x1.z) | ((unsigned)f2bf(x1.w)<<16);
        *(uint4*)(dst + (size_t)fid*8) = o;
    } else {
        int j = id - (NF0 + 3*NFH);
        if (j < PP*GATES) b0[j] = bih0[j] + bhh0[j];
        else if (j < 2*PP*GATES){ int q = j - PP*GATES; b1c[q] = bih1[q] + bhh1[q]; }
        else if (j < 2*PP*GATES + NSEQ){ psum[j - 2*PP*GATES] = 0.0f; }
    }
}

// ---- gather + concat -> bf16 X[pt][n][384], only t<=p ------------------------
__global__ void gather_x(const int* __restrict__ user_index,
                         const int* __restrict__ tpath, const int* __restrict__ ttype,
                         const int* __restrict__ trel,
                         const float* __restrict__ entity_emb, const float* __restrict__ relation_emb,
                         const float* __restrict__ user_emb, const float* __restrict__ news_emb,
                         const float* __restrict__ type_emb,
                         unsigned short* __restrict__ X){
    int id = blockIdx.x*256 + threadIdx.x;
    if (id >= PP*LL*NSEQ*48) return;
    int pt = id / (NSEQ*48); int rem = id % (NSEQ*48);
    int n = rem / 48, q = rem % 48;
    int p = pt / LL, t = pt % LL;
    if (t > p) return;
    int b = n / CC, c = n % CC;
    int u = user_index[b];
    int base = ((u*CC + c)*PP + p)*LL + t;
    int col = q*8;
    const float* s;
    if (q < 16){
        int ty = ttype[base]; int pi = tpath[base];
        const float* e = (ty==0)?user_emb:(ty==1)?news_emb:entity_emb;
        s = e + (size_t)pi*DD + col;
    } else if (q < 32){
        s = type_emb + (size_t)ttype[base]*DD + (col-128);
    } else {
        s = relation_emb + (size_t)trel[base]*DD + (col-256);
    }
    float4 x0 = *(const float4*)s, x1 = *(const float4*)(s+4);
    uint4 o;
    o.x = f2bf(x0.x) | ((unsigned)f2bf(x0.y)<<16);
    o.y = f2bf(x0.z) | ((unsigned)f2bf(x0.w)<<16);
    o.z = f2bf(x1.x) | ((unsigned)f2bf(x1.y)<<16);
    o.w = f2bf(x1.z) | ((unsigned)f2bf(x1.w)<<16);
    *(uint4*)(X + (size_t)(pt*NSEQ + n)*IN0 + col) = o;
}

// ---- fully fused: ih0 GEMM + 2-layer LSTM + scoring MLP ---------------------
// Block = (p, nt): 16 sequences, 512 threads = 8 waves.
// Wave w owns hidden units j = w*16 + (lane&15); its 4 acc tiles are the 4
// gates of those units (frag gt = gate*8 + w) -> gate combine is in-register.
__global__ __launch_bounds__(512) void lstm_v4(
    const unsigned short* __restrict__ X,
    const unsigned short* __restrict__ F0,   // Wih0 frags (streamed, L2)
    const unsigned short* __restrict__ F1,   // Whh0 frags (streamed, L2)
    const unsigned short* __restrict__ F2,   // Wih1 frags (reg-cached)
    const unsigned short* __restrict__ F3,   // Whh1 frags (reg-cached)
    const float* __restrict__ b0, const float* __restrict__ b1c,
    const float* __restrict__ W1, const float* __restrict__ b1v,
    const float* __restrict__ W2, const float* __restrict__ b2v,
    float* __restrict__ psum){
    __shared__ unsigned short h0T[16*HPAD];  // [row][hidden j], bf16
    __shared__ unsigned short h1T[16*HPAD];
    __shared__ float h1f[16*132];
    __shared__ float mlpb[16*17];

    int p = blockIdx.x / 40, nt = blockIdx.x % 40;
    int n0 = nt*16;
    int tid = threadIdx.x;
    int lane = tid & 63, w = tid >> 6;
    int r16 = lane & 15, qd = lane >> 4;
    int j = w*16 + r16;                      // this lane's hidden unit

    // reg-cache layer-1 weights: frag (kt, gate i) at gt = i*8 + w
    short8 f2r[16], f3r[16];
    {
        const unsigned short* F2p = F2 + (size_t)p*4*32*512 + lane*8;
        const unsigned short* F3p = F3 + (size_t)p*4*32*512 + lane*8;
        #pragma unroll
        for (int kt=0; kt<4; kt++)
            #pragma unroll
            for (int i=0;i<4;i++){
                f2r[kt*4+i] = *(const short8*)(F2p + (size_t)(kt*32 + i*8 + w)*512);
                f3r[kt*4+i] = *(const short8*)(F3p + (size_t)(kt*32 + i*8 + w)*512);
            }
    }
    float bL0[4], bL1[4];
    #pragma unroll
    for (int i=0;i<4;i++){
        int col = (i*8 + w)*16 + r16;
        bL0[i] = b0[p*GATES + col];
        bL1[i] = b1c[p*GATES + col];
    }
    const unsigned short* F0p = F0 + (size_t)p*12*32*512 + lane*8;
    const unsigned short* F1p = F1 + (size_t)p*4*32*512 + lane*8;

    float c0s[4] = {0,0,0,0}, c1s[4] = {0,0,0,0};

    for (int t=0; t<=p; t++){
        // ---- layer 0 preacts: bias + x_t @ Wih0^T (+ h0 @ Whh0^T) ----
        f32x4 acc[4];
        #pragma unroll
        for (int i=0;i<4;i++){
            float bb = bL0[i];
            f32x4 a; a[0]=bb; a[1]=bb; a[2]=bb; a[3]=bb; acc[i]=a;
        }
        const unsigned short* Xb = X + ((size_t)((p*LL+t)*NSEQ) + n0 + r16)*IN0 + qd*8;
        #pragma unroll
        for (int kt=0; kt<12; kt++){
            short8 a = *(const short8*)(Xb + kt*32);
            #pragma unroll
            for (int i=0;i<4;i++){
                short8 bfr = *(const short8*)(F0p + (size_t)(kt*32 + i*8 + w)*512);
                acc[i] = __builtin_amdgcn_mfma_f32_16x16x32_bf16(a, bfr, acc[i], 0,0,0);
            }
        }
        if (t > 0){
            #pragma unroll
            for (int kt=0; kt<4; kt++){
                short8 a = *(const short8*)(h0T + r16*HPAD + kt*32 + qd*8);
                #pragma unroll
                for (int i=0;i<4;i++){
                    short8 bfr = *(const short8*)(F1p + (size_t)(kt*32 + i*8 + w)*512);
                    acc[i] = __builtin_amdgcn_mfma_f32_16x16x32_bf16(a, bfr, acc[i], 0,0,0);
                }
            }
        }
        __syncthreads();   // all h0T reads (this t) done before overwrite
        // ---- combine layer 0 (in registers: acc[0..3] = i,f,g,o of unit j) ----
        #pragma unroll
        for (int v=0; v<4; v++){
            float cc = sigf(acc[1][v])*c0s[v] + sigf(acc[0][v])*tanhfast(acc[2][v]);
            c0s[v] = cc;
            h0T[(qd*4+v)*HPAD + j] = f2bf(sigf(acc[3][v])*tanhfast(cc));
        }
        __syncthreads();   // h0T visible
        // ---- layer 1 preacts: bias + h0 @ Wih1^T (+ h1 @ Whh1^T), regs ----
        #pragma unroll
        for (int i=0;i<4;i++){
            float bb = bL1[i];
            f32x4 a; a[0]=bb; a[1]=bb; a[2]=bb; a[3]=bb; acc[i]=a;
        }
        #pragma unroll
        for (int kt=0; kt<4; kt++){
            short8 a = *(const short8*)(h0T + r16*HPAD + kt*32 + qd*8);
            #pragma unroll
            for (int i=0;i<4;i++)
                acc[i] = __builtin_amdgcn_mfma_f32_16x16x32_bf16(a, f2r[kt*4+i], acc[i], 0,0,0);
        }
        if (t > 0){
            #pragma unroll
            for (int kt=0; kt<4; kt++){
                short8 a = *(const short8*)(h1T + r16*HPAD + kt*32 + qd*8);
                #pragma unroll
                for (int i=0;i<4;i++)
                    acc[i] = __builtin_amdgcn_mfma_f32_16x16x32_bf16(a, f3r[kt*4+i], acc[i], 0,0,0);
            }
        }
        __syncthreads();   // all h1T reads (this t) done before overwrite
        // ---- combine layer 1 ----
        #pragma unroll
        for (int v=0; v<4; v++){
            float cc = sigf(acc[1][v])*c1s[v] + sigf(acc[0][v])*tanhfast(acc[2][v]);
            c1s[v] = cc;
            float hh = sigf(acc[3][v])*tanhfast(cc);
            if (t < p) h1T[(qd*4+v)*HPAD + j] = f2bf(hh);
            else       h1f[(qd*4+v)*132 + j] = hh;
        }
    }
    __syncthreads();
    // ---- scoring MLP: sigmoid(relu(h1@W1^T+b1)@W2^T+b2), mean over paths ----
    if (tid < 256){
        int rr = tid & 15, hc = tid >> 4;
        const float* w1r = W1 + hc*DD;
        float acc = b1v[hc];
        #pragma unroll 4
        for (int k=0;k<DD;k++) acc = fmaf(h1f[rr*132 + k], w1r[k], acc);
        mlpb[hc*17 + rr] = fmaxf(acc, 0.0f);
    }
    __syncthreads();
    if (tid < 16){
        float s = b2v[0];
        #pragma unroll
        for (int h=0;h<16;h++) s = fmaf(mlpb[h*17 + tid], W2[h], s);
        atomicAdd(&psum[n0 + tid], 0.2f*sigf(s));
    }
}

// ---- final: emb_score + running mean (fp32 exact) ---------------------------
__global__ void final_kernel(const int* __restrict__ cand, const int* __restrict__ user_index,
                             const float* __restrict__ news_emb, const float* __restrict__ user_emb,
                             const float* __restrict__ psum, float* __restrict__ out){
    int b = blockIdx.x;
    int lane = threadIdx.x; // 64
    int u = user_index[b];
    const float* ue = user_emb + (size_t)u*DD;
    float cum = 0.0f;
    for (int c=0;c<CC;c++){
        int nb = cand[b*CC + c];
        const float* ne = news_emb + (size_t)nb*DD;
        float v = ne[lane]*ue[lane] + ne[lane+64]*ue[lane+64];
        #pragma unroll
        for (int off=32; off; off>>=1) v += __shfl_down(v, off, 64);
        if (lane == 0){
            cum += psum[b*CC + c];
            out[b*CC + c] = sigf(v) + cum/(float)(c+1);
        }
    }
}

extern "C" void kernel_launch(void* const* d_in, const int* in_sizes, int n_in,
                              void* d_out, int out_size, void* d_ws, size_t ws_size,
                              hipStream_t stream){
    const int* cand        = (const int*)d_in[0];
    const int* uidx        = (const int*)d_in[1];
    const int* tpath       = (const int*)d_in[2];
    const int* ttype       = (const int*)d_in[3];
    const int* trel        = (const int*)d_in[4];
    const float* entity_emb   = (const float*)d_in[5];
    const float* relation_emb = (const float*)d_in[6];
    const float* user_emb     = (const float*)d_in[7];
    const float* news_emb     = (const float*)d_in[8];
    const float* type_emb     = (const float*)d_in[9];
    const float* Wih0 = (const float*)d_in[10];
    const float* Whh0 = (const float*)d_in[11];
    const float* bih0 = (const float*)d_in[12];
    const float* bhh0 = (const float*)d_in[13];
    const float* Wih1 = (const float*)d_in[14];
    const float* Whh1 = (const float*)d_in[15];
    const float* bih1 = (const float*)d_in[16];
    const float* bhh1 = (const float*)d_in[17];
    const float* W1 = (const float*)d_in[18];
    const float* b1 = (const float*)d_in[19];
    const float* W2 = (const float*)d_in[20];
    const float* b2 = (const float*)d_in[21];
    float* out = (float*)d_out;

    char* ws = (char*)d_ws;
    unsigned short* F0 = (unsigned short*)ws;  ws += (size_t)PP*12*32*512*2;   // 1.97 MB
    unsigned short* F1 = (unsigned short*)ws;  ws += (size_t)PP*4*32*512*2;
    unsigned short* F2 = (unsigned short*)ws;  ws += (size_t)PP*4*32*512*2;
    unsigned short* F3 = (unsigned short*)ws;  ws += (size_t)PP*4*32*512*2;
    float* b0  = (float*)ws;                   ws += PP*GATES*4;
    float* b1c = (float*)ws;                   ws += PP*GATES*4;
    unsigned short* X = (unsigned short*)ws;   ws += (size_t)PP*LL*NSEQ*IN0*2; // 12.3 MB
    float* psum = (float*)ws;                  ws += NSEQ*4;

    prep_kernel<<<985,256,0,stream>>>(Wih0,Whh0,Wih1,Whh1,bih0,bhh0,bih1,bhh1,
                                      F0,F1,F2,F3,b0,b1c,psum);
    gather_x<<<3000,256,0,stream>>>(uidx,tpath,ttype,trel,entity_emb,relation_emb,
                                    user_emb,news_emb,type_emb,X);
    lstm_v4<<<200,512,0,stream>>>(X, F0, F1, F2, F3, b0, b1c, W1, b1, W2, b2, psum);
    final_kernel<<<BB,64,0,stream>>>(cand, uidx, news_emb, user_emb, psum, out);
}

// Round 5
// 233.935 us; speedup vs baseline: 1.2793x; 1.2793x over previous
//
#include <hip/hip_runtime.h>
#include <math.h>

#define BB   128
#define CC   5
#define PP   5
#define LL   5
#define DD   128
#define NSEQ 640
#define GATES 512
#define IN0  384
#define HPAD 136

typedef __attribute__((ext_vector_type(8))) short short8;   // 8 bf16
typedef __attribute__((ext_vector_type(4))) float f32x4;    // MFMA C/D

__device__ __forceinline__ float sigf(float x){ return 1.0f/(1.0f+__expf(-x)); }
__device__ __forceinline__ float tanhfast(float x){ return 1.0f - 2.0f/(__expf(2.0f*x)+1.0f); }

__device__ __forceinline__ unsigned short f2bf(float x){
    union { float f; unsigned u; } v; v.f = x;
    unsigned r = v.u + 0x7FFF + ((v.u >> 16) & 1);   // RNE
    return (unsigned short)(r >> 16);
}

// pt values with t<=p (15 of 25)
__device__ __constant__ int c_ptmap[15] = {0,5,6,10,11,12,15,16,17,18,20,21,22,23,24};

// ---- stage0: prep (weights->frags, biases, psum=0) + gather_x, one dispatch --
// blocks [0,985): prep; blocks [985, 985+1800): gather
__global__ void stage0_kernel(const float* __restrict__ Wih0, const float* __restrict__ Whh0,
                              const float* __restrict__ Wih1, const float* __restrict__ Whh1,
                              const float* __restrict__ bih0, const float* __restrict__ bhh0,
                              const float* __restrict__ bih1, const float* __restrict__ bhh1,
                              unsigned short* __restrict__ F0, unsigned short* __restrict__ F1,
                              unsigned short* __restrict__ F2, unsigned short* __restrict__ F3,
                              float* __restrict__ b0, float* __restrict__ b1c,
                              float* __restrict__ psum,
                              const int* __restrict__ user_index,
                              const int* __restrict__ tpath, const int* __restrict__ ttype,
                              const int* __restrict__ trel,
                              const float* __restrict__ entity_emb, const float* __restrict__ relation_emb,
                              const float* __restrict__ user_emb, const float* __restrict__ news_emb,
                              const float* __restrict__ type_emb,
                              unsigned short* __restrict__ X){
    int bx = blockIdx.x;
    if (bx < 985){
        // ---------------- prep ----------------
        int id = bx*256 + threadIdx.x;
        const int NF0 = PP*12*32*64;     // 122880
        const int NFH = PP*4*32*64;      // 40960
        if (id < NF0 + 3*NFH){
            const float* src; unsigned short* dst; int K, KT, fid;
            if (id < NF0){ src = Wih0; dst = F0; K = IN0; KT = 12; fid = id; }
            else {
                int j = id - NF0; int m = j / NFH; fid = j % NFH; K = DD; KT = 4;
                src = (m==0)?Whh0:(m==1)?Wih1:Whh1;
                dst = (m==0)?F1:(m==1)?F2:F3;
            }
            int lane = fid & 63; int rem = fid >> 6;
            int gt = rem & 31; rem >>= 5;
            int kt = rem % KT; int p = rem / KT;
            int g  = gt*16 + (lane & 15);
            int k0 = kt*32 + (lane >> 4)*8;
            const float* s = src + (size_t)(p*GATES + g)*K + k0;
            float4 x0 = *(const float4*)s;
            float4 x1 = *(const float4*)(s+4);
            uint4 o;
            o.x = f2bf(x0.x) | ((unsigned)f2bf(x0.y)<<16);
            o.y = f2bf(x0.z) | ((unsigned)f2bf(x0.w)<<16);
            o.z = f2bf(x1.x) | ((unsigned)f2bf(x1.y)<<16);
            o.w = f2bf(x1.z) | ((unsigned)f2bf(x1.w)<<16);
            *(uint4*)(dst + (size_t)fid*8) = o;
        } else {
            int j = id - (NF0 + 3*NFH);
            if (j < PP*GATES) b0[j] = bih0[j] + bhh0[j];
            else if (j < 2*PP*GATES){ int q = j - PP*GATES; b1c[q] = bih1[q] + bhh1[q]; }
            else if (j < 2*PP*GATES + NSEQ){ psum[j - 2*PP*GATES] = 0.0f; }
        }
    } else {
        // ---------------- gather (only t<=p slices) ----------------
        int id = (bx - 985)*256 + threadIdx.x;   // 15*640*48 = 460800 items
        if (id >= 15*NSEQ*48) return;
        int ptIdx = id / (NSEQ*48); int rem = id % (NSEQ*48);
        int n = rem / 48, q = rem % 48;
        int pt = c_ptmap[ptIdx];
        int p = pt / LL, t = pt % LL;
        int b = n / CC, c = n % CC;
        int u = user_index[b];
        int base = ((u*CC + c)*PP + p)*LL + t;
        int col = q*8;
        const float* s;
        if (q < 16){
            int ty = ttype[base]; int pi = tpath[base];
            const float* e = (ty==0)?user_emb:(ty==1)?news_emb:entity_emb;
            s = e + (size_t)pi*DD + col;
        } else if (q < 32){
            s = type_emb + (size_t)ttype[base]*DD + (col-128);
        } else {
            s = relation_emb + (size_t)trel[base]*DD + (col-256);
        }
        float4 x0 = *(const float4*)s, x1 = *(const float4*)(s+4);
        uint4 o;
        o.x = f2bf(x0.x) | ((unsigned)f2bf(x0.y)<<16);
        o.y = f2bf(x0.z) | ((unsigned)f2bf(x0.w)<<16);
        o.z = f2bf(x1.x) | ((unsigned)f2bf(x1.y)<<16);
        o.w = f2bf(x1.z) | ((unsigned)f2bf(x1.w)<<16);
        *(uint4*)(X + (size_t)(pt*NSEQ + n)*IN0 + col) = o;
    }
}

// ---- tiled MFMA GEMM: G0c (C-frag layout) = X @ Wih0^T ----------------------
// grid: 15 ptIdx x 10 m64 x 8 nch. Block 256 thr: 64 rows x 64 cols, B in LDS.
// G0c[tile16][gt][lane][4], tile16 = pt*40 + row/16
__global__ __launch_bounds__(256) void gemm_ih0_v5(const unsigned short* __restrict__ X,
                                                   const unsigned short* __restrict__ F0,
                                                   float* __restrict__ G0c){
    __shared__ unsigned short Bs[12*4*512];   // 48 KB
    int bx = blockIdx.x;
    int nch = bx & 7;
    int m64 = (bx >> 3) % 10;
    int pt  = c_ptmap[bx / 80];
    int p = pt / LL;
    int tid = threadIdx.x, lane = tid & 63, w = tid >> 6;
    int r16 = lane & 15, qd = lane >> 4;

    const unsigned short* Fp = F0 + (((size_t)p*12)*32 + nch*4)*512;
    uint4 breg[12];
    #pragma unroll
    for (int j=0;j<12;j++)
        breg[j] = *(const uint4*)(Fp + (size_t)j*32*512 + tid*8);
    #pragma unroll
    for (int j=0;j<12;j++)
        *(uint4*)(Bs + j*2048 + tid*8) = breg[j];
    __syncthreads();

    f32x4 acc[4];
    #pragma unroll
    for (int i=0;i<4;i++) acc[i] = (f32x4)0.0f;
    const unsigned short* Xb = X + ((size_t)pt*NSEQ + m64*64 + w*16 + r16)*IN0 + qd*8;
    #pragma unroll
    for (int kt=0; kt<12; kt++){
        short8 a = *(const short8*)(Xb + kt*32);
        #pragma unroll
        for (int i=0;i<4;i++){
            short8 bfr = *(const short8*)(Bs + (kt*4+i)*512 + lane*8);
            acc[i] = __builtin_amdgcn_mfma_f32_16x16x32_bf16(a, bfr, acc[i], 0,0,0);
        }
    }
    int tile16 = pt*40 + m64*4 + w;
    float* dst = G0c + (((size_t)tile16*32 + nch*4)*64 + lane)*4;
    #pragma unroll
    for (int i=0;i<4;i++)
        *(f32x4*)(dst + (size_t)i*256) = acc[i];
}

// ---- fused 2-layer LSTM: slab-prefetch + in-register gate combine -----------
// Wave w owns hidden units j = w*16 + (lane&15); frag gt = gate*8 + w so
// acc[0..3] = (i,f,g,o) preacts of unit j for rows qd*4+v. 3 barriers/t.
__global__ __launch_bounds__(512) void lstm_v5(
    const float* __restrict__ G0c,
    const unsigned short* __restrict__ F1,   // Whh0 frags (streamed, L2)
    const unsigned short* __restrict__ F2,   // Wih1 frags (reg-cached)
    const unsigned short* __restrict__ F3,   // Whh1 frags (reg-cached)
    const float* __restrict__ b0, const float* __restrict__ b1c,
    const float* __restrict__ W1, const float* __restrict__ b1v,
    const float* __restrict__ W2, const float* __restrict__ b2v,
    float* __restrict__ psum){
    __shared__ unsigned short h0T[16*HPAD];  // [row][hidden j], bf16
    __shared__ unsigned short h1T[16*HPAD];
    __shared__ float h1f[16*132];
    __shared__ float mlpb[16*17];

    int p = blockIdx.x / 40, nt = blockIdx.x % 40;
    int n0 = nt*16;
    int tid = threadIdx.x;
    int lane = tid & 63, w = tid >> 6;
    int r16 = lane & 15, qd = lane >> 4;
    int j = w*16 + r16;

    // reg-cache layer-1 weights: frag (kt, gate i) at gt = i*8 + w
    short8 f2r[16], f3r[16];
    {
        const unsigned short* F2p = F2 + (size_t)p*4*32*512 + lane*8;
        const unsigned short* F3p = F3 + (size_t)p*4*32*512 + lane*8;
        #pragma unroll
        for (int kt=0; kt<4; kt++)
            #pragma unroll
            for (int i=0;i<4;i++){
                f2r[kt*4+i] = *(const short8*)(F2p + (size_t)(kt*32 + i*8 + w)*512);
                f3r[kt*4+i] = *(const short8*)(F3p + (size_t)(kt*32 + i*8 + w)*512);
            }
    }
    float bL0[4], bL1[4];
    #pragma unroll
    for (int i=0;i<4;i++){
        int col = (i*8 + w)*16 + r16;
        bL0[i] = b0[p*GATES + col];
        bL1[i] = b1c[p*GATES + col];
    }
    const unsigned short* F1p = F1 + (size_t)p*4*32*512 + lane*8;

    // prefetch slab t=0 (C-layout: this wave's gate tiles gt=i*8+w)
    f32x4 pf[4];
    {
        const float* slab = G0c + (size_t)((p*LL + 0)*40 + nt)*8192;
        #pragma unroll
        for (int i=0;i<4;i++) pf[i] = *(const f32x4*)(slab + ((i*8+w)*64 + lane)*4);
    }
    float c0s[4] = {0,0,0,0}, c1s[4] = {0,0,0,0};

    for (int t=0; t<=p; t++){
        // ---- layer 0 preacts: slab + bias (+ h0 @ Whh0^T) ----
        f32x4 acc[4];
        #pragma unroll
        for (int i=0;i<4;i++){
            f32x4 a = pf[i]; float bb = bL0[i];
            a[0]+=bb; a[1]+=bb; a[2]+=bb; a[3]+=bb; acc[i]=a;
        }
        if (t < p){
            const float* ns = G0c + (size_t)((p*LL + t + 1)*40 + nt)*8192;
            #pragma unroll
            for (int i=0;i<4;i++) pf[i] = *(const f32x4*)(ns + ((i*8+w)*64 + lane)*4);
        }
        if (t > 0){
            #pragma unroll
            for (int kt=0; kt<4; kt++){
                short8 a = *(const short8*)(h0T + r16*HPAD + kt*32 + qd*8);
                #pragma unroll
                for (int i=0;i<4;i++){
                    short8 bfr = *(const short8*)(F1p + (size_t)(kt*32 + i*8 + w)*512);
                    acc[i] = __builtin_amdgcn_mfma_f32_16x16x32_bf16(a, bfr, acc[i], 0,0,0);
                }
            }
        }
        __syncthreads();   // all reads of h0T(t-1) done
        // ---- combine layer 0 (registers) ----
        #pragma unroll
        for (int v=0; v<4; v++){
            float cc = sigf(acc[1][v])*c0s[v] + sigf(acc[0][v])*tanhfast(acc[2][v]);
            c0s[v] = cc;
            h0T[(qd*4+v)*HPAD + j] = f2bf(sigf(acc[3][v])*tanhfast(cc));
        }
        __syncthreads();   // h0T(t) visible
        // ---- layer 1 preacts: bias + h0 @ Wih1^T (+ h1 @ Whh1^T), regs ----
        #pragma unroll
        for (int i=0;i<4;i++){
            float bb = bL1[i];
            f32x4 a; a[0]=bb; a[1]=bb; a[2]=bb; a[3]=bb; acc[i]=a;
        }
        #pragma unroll
        for (int kt=0; kt<4; kt++){
            short8 a = *(const short8*)(h0T + r16*HPAD + kt*32 + qd*8);
            #pragma unroll
            for (int i=0;i<4;i++)
                acc[i] = __builtin_amdgcn_mfma_f32_16x16x32_bf16(a, f2r[kt*4+i], acc[i], 0,0,0);
        }
        if (t > 0){
            #pragma unroll
            for (int kt=0; kt<4; kt++){
                short8 a = *(const short8*)(h1T + r16*HPAD + kt*32 + qd*8);
                #pragma unroll
                for (int i=0;i<4;i++)
                    acc[i] = __builtin_amdgcn_mfma_f32_16x16x32_bf16(a, f3r[kt*4+i], acc[i], 0,0,0);
            }
        }
        __syncthreads();   // all reads of h1T(t-1) done
        // ---- combine layer 1 (registers) ----
        #pragma unroll
        for (int v=0; v<4; v++){
            float cc = sigf(acc[1][v])*c1s[v] + sigf(acc[0][v])*tanhfast(acc[2][v]);
            c1s[v] = cc;
            float hh = sigf(acc[3][v])*tanhfast(cc);
            if (t < p) h1T[(qd*4+v)*HPAD + j] = f2bf(hh);
            else       h1f[(qd*4+v)*132 + j] = hh;
        }
    }
    __syncthreads();
    // ---- scoring MLP: sigmoid(relu(h1@W1^T+b1)@W2^T+b2), mean over paths ----
    if (tid < 256){
        int rr = tid & 15, hc = tid >> 4;
        const float* w1r = W1 + hc*DD;
        float acc = b1v[hc];
        #pragma unroll 4
        for (int k=0;k<DD;k++) acc = fmaf(h1f[rr*132 + k], w1r[k], acc);
        mlpb[hc*17 + rr] = fmaxf(acc, 0.0f);
    }
    __syncthreads();
    if (tid < 16){
        float s = b2v[0];
        #pragma unroll
        for (int h=0;h<16;h++) s = fmaf(mlpb[h*17 + tid], W2[h], s);
        atomicAdd(&psum[n0 + tid], 0.2f*sigf(s));
    }
}

// ---- final: emb_score + running mean (fp32 exact) ---------------------------
__global__ void final_kernel(const int* __restrict__ cand, const int* __restrict__ user_index,
                             const float* __restrict__ news_emb, const float* __restrict__ user_emb,
                             const float* __restrict__ psum, float* __restrict__ out){
    int b = blockIdx.x;
    int lane = threadIdx.x; // 64
    int u = user_index[b];
    const float* ue = user_emb + (size_t)u*DD;
    float cum = 0.0f;
    for (int c=0;c<CC;c++){
        int nb = cand[b*CC + c];
        const float* ne = news_emb + (size_t)nb*DD;
        float v = ne[lane]*ue[lane] + ne[lane+64]*ue[lane+64];
        #pragma unroll
        for (int off=32; off; off>>=1) v += __shfl_down(v, off, 64);
        if (lane == 0){
            cum += psum[b*CC + c];
            out[b*CC + c] = sigf(v) + cum/(float)(c+1);
        }
    }
}

extern "C" void kernel_launch(void* const* d_in, const int* in_sizes, int n_in,
                              void* d_out, int out_size, void* d_ws, size_t ws_size,
                              hipStream_t stream){
    const int* cand        = (const int*)d_in[0];
    const int* uidx        = (const int*)d_in[1];
    const int* tpath       = (const int*)d_in[2];
    const int* ttype       = (const int*)d_in[3];
    const int* trel        = (const int*)d_in[4];
    const float* entity_emb   = (const float*)d_in[5];
    const float* relation_emb = (const float*)d_in[6];
    const float* user_emb     = (const float*)d_in[7];
    const float* news_emb     = (const float*)d_in[8];
    const float* type_emb     = (const float*)d_in[9];
    const float* Wih0 = (const float*)d_in[10];
    const float* Whh0 = (const float*)d_in[11];
    const float* bih0 = (const float*)d_in[12];
    const float* bhh0 = (const float*)d_in[13];
    const float* Wih1 = (const float*)d_in[14];
    const float* Whh1 = (const float*)d_in[15];
    const float* bih1 = (const float*)d_in[16];
    const float* bhh1 = (const float*)d_in[17];
    const float* W1 = (const float*)d_in[18];
    const float* b1 = (const float*)d_in[19];
    const float* W2 = (const float*)d_in[20];
    const float* b2 = (const float*)d_in[21];
    float* out = (float*)d_out;

    char* ws = (char*)d_ws;
    unsigned short* F0 = (unsigned short*)ws;  ws += (size_t)PP*12*32*512*2;   // 1.97 MB
    unsigned short* F1 = (unsigned short*)ws;  ws += (size_t)PP*4*32*512*2;
    unsigned short* F2 = (unsigned short*)ws;  ws += (size_t)PP*4*32*512*2;
    unsigned short* F3 = (unsigned short*)ws;  ws += (size_t)PP*4*32*512*2;
    float* b0  = (float*)ws;                   ws += PP*GATES*4;
    float* b1c = (float*)ws;                   ws += PP*GATES*4;
    unsigned short* X = (unsigned short*)ws;   ws += (size_t)PP*LL*NSEQ*IN0*2; // 12.3 MB
    float* G0c = (float*)ws;                   ws += (size_t)PP*LL*NSEQ*GATES*4; // 32.8 MB
    float* psum = (float*)ws;                  ws += NSEQ*4;

    stage0_kernel<<<985+1800,256,0,stream>>>(Wih0,Whh0,Wih1,Whh1,bih0,bhh0,bih1,bhh1,
                                             F0,F1,F2,F3,b0,b1c,psum,
                                             uidx,tpath,ttype,trel,entity_emb,relation_emb,
                                             user_emb,news_emb,type_emb,X);
    gemm_ih0_v5<<<1200,256,0,stream>>>(X, F0, G0c);
    lstm_v5<<<200,512,0,stream>>>(G0c, F1, F2, F3, b0, b1c, W1, b1, W2, b2, psum);
    final_kernel<<<BB,64,0,stream>>>(cand, uidx, news_emb, user_emb, psum, out);
}